// Round 10
// baseline (114.407 us; speedup 1.0000x reference)
//
#include <hip/hip_runtime.h>
#include <math.h>

#define HEADS   4
#define DH      32
#define NB      4096      // tokens per batch (D*H*W)
#define BATCH   2
#define C_IN    128
#define QKV_COLS 384
#define TOTROWS 8192      // BATCH * NB
#define ATT_EPS 1e-12f
#define C1      14.42695040888963f   // SCALE * log2(e), prefolded into Q
#define QROWS   4         // rows per qkv block (grid 2048)
#define OROWS   4         // rows per outproj block (grid 2048)

typedef __attribute__((ext_vector_type(16))) float f32x16;
typedef __attribute__((ext_vector_type(8)))  short short8;
typedef _Float16 f16x8 __attribute__((ext_vector_type(8)));
typedef __fp16 fp16x2 __attribute__((ext_vector_type(2)));   // cvt_pkrtz return type
typedef unsigned short u16;

__device__ __forceinline__ float tr16(float a) {        // truncate to bf16 (bits)
  return __uint_as_float(__float_as_uint(a) & 0xFFFF0000u);
}
__device__ __forceinline__ unsigned pkhi(float a, float b) {  // pack 2 bf16 (trunc)
  return (__float_as_uint(a) >> 16) | (__float_as_uint(b) & 0xFFFF0000u);
}
__device__ __forceinline__ u16 b16(float a) {
  return (u16)(__float_as_uint(a) >> 16);
}
// pack 2 f32 -> 2 f16 (RTZ), single instruction
union Uh2 { fp16x2 h; unsigned u; };
__device__ __forceinline__ unsigned pkf16(float a, float b) {
  Uh2 t; t.h = __builtin_amdgcn_cvt_pkrtz(a, b); return t.u;
}
union U8 { unsigned u[4]; short8 s8; };
__device__ __forceinline__ short8 mk8(unsigned a, unsigned b, unsigned c, unsigned d) {
  U8 t; t.u[0] = a; t.u[1] = b; t.u[2] = c; t.u[3] = d; return t.s8;
}
union U8h { unsigned u[4]; f16x8 h8; };
__device__ __forceinline__ f16x8 mk8h(unsigned a, unsigned b, unsigned c, unsigned d) {
  U8h t; t.u[0] = a; t.u[1] = b; t.u[2] = c; t.u[3] = d; return t.h8;
}
// v_permlane32_swap_b32 a,b. SAFE ONLY when a and b hold distinct values
// (else regalloc may coalesce them into one register) — see R4 post-mortem.
__device__ __forceinline__ void pl32swap(unsigned& a, unsigned& b) {
  asm("v_permlane32_swap_b32 %0, %1" : "+v"(a), "+v"(b));
}
#define GL16(gp, lp)                                                        \
  __builtin_amdgcn_global_load_lds(                                         \
      (const __attribute__((address_space(1))) void*)(gp),                  \
      (__attribute__((address_space(3))) void*)(lp), 16, 0, 0)

// ---------------------------------------------------------------------------
// QKV GEMM (x @ w_qkv) + fused L2-normalize of q,k. 4 rows/block, 2048 blocks
// (30 waves/CU; R8's 32-row version was 13% occupancy / latency-bound).
// float4 partial accumulators break the serial FMA chain. Writes:
//   Qs  fp32 [bh][n][32], pre-scaled by C1
//   Khi/Klo u16 [bh][n][32]   (bf16 truncation hi + residual lo)
//   VT16 u16 [bh][32][n]      (fp16 RTZ, pre-transposed)
// ---------------------------------------------------------------------------
__global__ __launch_bounds__(384) void qkv_kernel(
    const float* __restrict__ x, const float* __restrict__ w,
    float* __restrict__ Qs, u16* __restrict__ Khi, u16* __restrict__ Klo,
    u16* __restrict__ VT16) {
  __shared__ float xR[QROWS][132];   // row-major tile, 528B rows (16B-aligned)
  const int tid = threadIdx.x;
  const int r0  = blockIdx.x * QROWS;

  if (tid < QROWS * 32) {
    const int r = tid >> 5, c4 = tid & 31;
    const float4 v4 = ((const float4*)(x + (size_t)(r0 + r) * C_IN))[c4];
    *(float4*)&xR[r][c4 * 4] = v4;
  }
  __syncthreads();

  float4 a4[QROWS];
#pragma unroll
  for (int r = 0; r < QROWS; ++r) a4[r] = make_float4(0.f, 0.f, 0.f, 0.f);

  for (int c4 = 0; c4 < 32; ++c4) {
    const float wv0 = w[(c4 * 4 + 0) * QKV_COLS + tid];
    const float wv1 = w[(c4 * 4 + 1) * QKV_COLS + tid];
    const float wv2 = w[(c4 * 4 + 2) * QKV_COLS + tid];
    const float wv3 = w[(c4 * 4 + 3) * QKV_COLS + tid];
#pragma unroll
    for (int r = 0; r < QROWS; ++r) {
      const float4 xv = *(const float4*)&xR[r][c4 * 4];   // broadcast read
      a4[r].x = fmaf(xv.x, wv0, a4[r].x);
      a4[r].y = fmaf(xv.y, wv1, a4[r].y);
      a4[r].z = fmaf(xv.z, wv2, a4[r].z);
      a4[r].w = fmaf(xv.w, wv3, a4[r].w);
    }
  }

  float acc[QROWS];
#pragma unroll
  for (int r = 0; r < QROWS; ++r)
    acc[r] = (a4[r].x + a4[r].y) + (a4[r].z + a4[r].w);

  const int part = tid >> 7;   // 0=q 1=k 2=v (wave-uniform)
  if (part < 2) {
#pragma unroll
    for (int r = 0; r < QROWS; ++r) {
      float s = acc[r] * acc[r];
      s += __shfl_xor(s, 1, 32);
      s += __shfl_xor(s, 2, 32);
      s += __shfl_xor(s, 4, 32);
      s += __shfl_xor(s, 8, 32);
      s += __shfl_xor(s, 16, 32);
      acc[r] *= 1.0f / fmaxf(sqrtf(s), ATT_EPS);
    }
  }

  const int h = (tid >> 5) & 3, d = tid & 31;
  const int b = r0 >> 12, n0 = r0 & (NB - 1);
  const int bh = b * HEADS + h;
  if (part == 0) {
    float* dst = Qs + ((size_t)bh * NB + n0) * DH + d;
#pragma unroll
    for (int r = 0; r < QROWS; ++r) dst[(size_t)r * DH] = acc[r] * C1;
  } else if (part == 1) {
    const size_t kb = ((size_t)bh * NB + n0) * DH + d;
#pragma unroll
    for (int r = 0; r < QROWS; ++r) {
      const float kv = acc[r];
      Khi[kb + (size_t)r * DH] = b16(kv);
      Klo[kb + (size_t)r * DH] = b16(kv - tr16(kv));
    }
  } else {
    const size_t vb = ((size_t)bh * DH + d) * NB + n0;
#pragma unroll
    for (int r = 0; r < QROWS; r += 4) {
      uint2 hv;
      hv.x = pkf16(acc[r + 0], acc[r + 1]);
      hv.y = pkf16(acc[r + 2], acc[r + 3]);
      *(uint2*)(VT16 + vb + r) = hv;
    }
  }
}

// ---------------------------------------------------------------------------
// MFMA flash attention, fixed softmax max (|q.k|<=1 after L2 norm => log2
// scores bounded by C1; 2^-C1 cancels in O/L). No max tracking, no rescale.
// grid 512 (1-D), block 512 = 8 waves = 2 q-subtiles x 4 KV-splits.
// XCD-aware decode: bh = id&7 (8 XCDs, id%8 = XCD) so each XCD's L2 caches
// exactly one bh's K/V panels (768KB << 4MB). R9 measured 26.6MB FETCH vs
// ~6MB compulsory = L2 thrash from x%8 XCD round-robin of the (64,8) grid.
// QK^T: bf16 3-term (hi/lo); PV: fp16 single-term.
// ---------------------------------------------------------------------------
__global__ __launch_bounds__(512, 4) void attn_kernel(
    const float* __restrict__ Qs,
    const u16* __restrict__ Khi, const u16* __restrict__ Klo,
    const u16* __restrict__ VT16, float* __restrict__ AO) {
  // [buf][split][plane: 0=Khi 1=Klo 2=V16][2048B]  = 48 KB total
  __shared__ __align__(16) char sbuf[2][4][3][2048];

  const int tid  = threadIdx.x;
  const int lane = tid & 63;
  const int w    = tid >> 6;
  const int su   = w & 3;           // KV split
  const int u    = w >> 2;          // q-subtile
  const int q    = lane & 31;
  const int hi   = lane >> 5;
  const int bh   = blockIdx.x & 7;  // XCD-pinned panel
  const int qp   = blockIdx.x >> 3; // q-pair tile 0..63

  // ---- Q fragments (hi/lo truncation split); Q pre-scaled by C1 ----
  const int nrow = qp * 64 + u * 32 + q;
  const float* qrow = Qs + ((size_t)bh * NB + nrow) * DH;
  short8 fqh[2], fql[2];
#pragma unroll
  for (int sl = 0; sl < 2; ++sl) {
    const int d0 = sl * 16 + hi * 8;
    const float4 a = *(const float4*)(qrow + d0);
    const float4 b = *(const float4*)(qrow + d0 + 4);
    fqh[sl] = mk8(pkhi(a.x, a.y), pkhi(a.z, a.w), pkhi(b.x, b.y), pkhi(b.z, b.w));
    fql[sl] = mk8(pkhi(a.x - tr16(a.x), a.y - tr16(a.y)),
                  pkhi(a.z - tr16(a.z), a.w - tr16(a.w)),
                  pkhi(b.x - tr16(b.x), b.y - tr16(b.y)),
                  pkhi(b.z - tr16(b.z), b.w - tr16(b.w)));
  }

  // ---- staging map: flat i = tid + it*512 over 12 planes x 2048B ----
  const u16* gp[3]; int gst[3], ldso[3];
#pragma unroll
  for (int it = 0; it < 3; ++it) {
    const int i    = tid + it * 512;
    const int pidx = i >> 7;            // plane 0..11 = split*3 + {Khi,Klo,V}
    const int sp   = pidx / 3;
    const int pl   = pidx - sp * 3;
    const int s    = i & 127;
    const int rtt  = s >> 2;            // row within plane (key or d)
    const int ps   = s & 3;             // physical 16B slot
    const int slot = ((ps ^ ((rtt >> 1) & 3)) << 3);   // logical, u16 units
    if (pl < 2) {   // K planes: row = key, advance 32 keys/tile
      const u16* base = pl ? Klo : Khi;
      gp[it]  = base + (size_t)bh * NB * DH + (size_t)(sp * 1024 + rtt) * DH + slot;
      gst[it] = 32 * DH;
    } else {        // V plane: row = d (NB-long), advance 32 u16/tile
      gp[it]  = VT16 + (size_t)bh * DH * NB + (size_t)rtt * NB + sp * 1024 + slot;
      gst[it] = 32;
    }
    ldso[it] = i * 16;
  }
  char* const sb = (char*)sbuf;
  auto stage = [&](int buf) {
#pragma unroll
    for (int it = 0; it < 3; ++it) {
      GL16(gp[it], sb + buf * 24576 + ldso[it]);
      gp[it] += gst[it];
    }
  };

  // read offsets (swizzled), constant per wave
  const int swq = (q >> 1) & 3;
  int koff[2];
#pragma unroll
  for (int i = 0; i < 2; ++i) koff[i] = q * 64 + (((i * 2 + hi) ^ swq) << 4);

  f32x16 oa;
#pragma unroll
  for (int r = 0; r < 16; ++r) oa[r] = 0.f;
  float lrun = 0.f;

  stage(0);
  __syncthreads();

  for (int t = 0; t < 32; ++t) {
    const int cur = t & 1;
    if (t < 31) stage(cur ^ 1);

    const char* cb  = sb + cur * 24576 + su * 6144;
    const char* ckh = cb;
    const char* ckl = cb + 2048;
    const char* cv  = cb + 4096;

    // ---- QK^T (3-term hi/lo bf16), S^T[key][q] ----
    f32x16 sa;
#pragma unroll
    for (int r = 0; r < 16; ++r) sa[r] = 0.f;
    __builtin_amdgcn_s_setprio(1);
#pragma unroll
    for (int sl = 0; sl < 2; ++sl) {
      const short8 fkh = *(const short8*)(ckh + koff[sl]);
      const short8 fkl = *(const short8*)(ckl + koff[sl]);
      sa = __builtin_amdgcn_mfma_f32_32x32x16_bf16(fkh, fqh[sl], sa, 0, 0, 0);
      sa = __builtin_amdgcn_mfma_f32_32x32x16_bf16(fkl, fqh[sl], sa, 0, 0, 0);
      sa = __builtin_amdgcn_mfma_f32_32x32x16_bf16(fkh, fql[sl], sa, 0, 0, 0);
    }
    __builtin_amdgcn_s_setprio(0);

    // ---- softmax, fixed max: raw v_exp_f32 (inputs bounded by ±2*C1) ----
    float e[16], lsum = 0.f;
#pragma unroll
    for (int r = 0; r < 16; ++r) {
      e[r] = __builtin_amdgcn_exp2f(sa[r]);
      lsum += e[r];
    }
    lrun += lsum;

    // ---- P pack (fp16 RTZ) + permlane32_swap distribution, PV 1-term ----
    __builtin_amdgcn_s_setprio(1);
#pragma unroll
    for (int m = 0; m < 2; ++m) {
      const float* eb = e + 8 * m;
      unsigned x0 = pkf16(eb[0], eb[1]), x1 = pkf16(eb[2], eb[3]);
      unsigned y0 = pkf16(eb[4], eb[5]), y1 = pkf16(eb[6], eb[7]);
      pl32swap(x0, y0);    // distinct values: safe
      pl32swap(x1, y1);
      const f16x8 fP = mk8h(x0, x1, y0, y1);
      const f16x8 fv = *(const f16x8*)(cv + koff[m]);
      oa = __builtin_amdgcn_mfma_f32_32x32x16_f16(fv, fP, oa, 0, 0, 0);
    }
    __builtin_amdgcn_s_setprio(0);
    __syncthreads();   // drains gload_lds (implicit vmcnt(0)) + LDS reads
  }

  // ---- 4-way split merge via LDS (plain sums — common fixed max) ----
  // Alias merge arrays onto the (dead) staging LDS.
  float* const mO = (float*)sbuf;             // [u][s(0..2)][q][33]
  float* const mL = mO + 2 * 3 * 32 * 33;     // [u][s][q]
  const float Lfull = lrun + __shfl_xor(lrun, 32);
  if (su != 0) {
    const int sidx = (u * 3 + (su - 1)) * 32 + q;
    if (hi == 0) mL[sidx] = Lfull;
#pragma unroll
    for (int r = 0; r < 16; ++r) {
      const int d = (r & 3) + 8 * (r >> 2) + 4 * hi;
      mO[sidx * 33 + d] = oa[r];
    }
  }
  __syncthreads();
  if (su == 0) {
    float Lt = Lfull;
#pragma unroll
    for (int s = 0; s < 3; ++s) Lt += mL[(u * 3 + s) * 32 + q];
    const float inv = 1.0f / Lt;
    const int b = bh >> 2, h = bh & 3;
    float* dst = AO + ((size_t)(b * NB + nrow)) * 128 + h * DH;
#pragma unroll
    for (int r = 0; r < 16; ++r) {
      const int d = (r & 3) + 8 * (r >> 2) + 4 * hi;
      float v = oa[r];
#pragma unroll
      for (int s = 0; s < 3; ++s) v += mO[((u * 3 + s) * 32 + q) * 33 + d];
      dst[d] = v * inv;
    }
  }
}

// ---------------------------------------------------------------------------
// out-proj GEMM: AO[8192][128] @ w_out[128][128] + b_out (in-place safe:
// block stages its 4 rows in LDS before overwriting them). 2048 blocks
// = 16 waves/CU (R9's 1024-block version was 8 waves/CU, latency-bound).
// ---------------------------------------------------------------------------
__global__ __launch_bounds__(128) void outproj_kernel(
    const float* __restrict__ AO, const float* __restrict__ w,
    const float* __restrict__ bias, float* __restrict__ out) {
  __shared__ float xR[OROWS][132];
  const int tid = threadIdx.x;
  const int r0  = blockIdx.x * OROWS;

  {
    const int r = tid >> 5, c4 = tid & 31;
    const float4 v4 = ((const float4*)(AO + (size_t)(r0 + r) * 128))[c4];
    *(float4*)&xR[r][c4 * 4] = v4;
  }
  __syncthreads();

  float4 a4[OROWS];
#pragma unroll
  for (int r = 0; r < OROWS; ++r) a4[r] = make_float4(0.f, 0.f, 0.f, 0.f);

  for (int c4 = 0; c4 < 32; ++c4) {
    const float wv0 = w[(c4 * 4 + 0) * 128 + tid];
    const float wv1 = w[(c4 * 4 + 1) * 128 + tid];
    const float wv2 = w[(c4 * 4 + 2) * 128 + tid];
    const float wv3 = w[(c4 * 4 + 3) * 128 + tid];
#pragma unroll
    for (int r = 0; r < OROWS; ++r) {
      const float4 xv = *(const float4*)&xR[r][c4 * 4];   // broadcast read
      a4[r].x = fmaf(xv.x, wv0, a4[r].x);
      a4[r].y = fmaf(xv.y, wv1, a4[r].y);
      a4[r].z = fmaf(xv.z, wv2, a4[r].z);
      a4[r].w = fmaf(xv.w, wv3, a4[r].w);
    }
  }

  const float bv = bias[tid];
#pragma unroll
  for (int r = 0; r < OROWS; ++r) {
    const float acc = (a4[r].x + a4[r].y) + (a4[r].z + a4[r].w);
    out[(size_t)(r0 + r) * 128 + tid] = acc + bv;
  }
}

// ---------------------------------------------------------------------------
extern "C" void kernel_launch(void* const* d_in, const int* in_sizes, int n_in,
                              void* d_out, int out_size, void* d_ws, size_t ws_size,
                              hipStream_t stream) {
  (void)in_sizes; (void)n_in; (void)out_size; (void)ws_size;
  const float* x     = (const float*)d_in[0];
  const float* w_qkv = (const float*)d_in[1];
  const float* w_out = (const float*)d_in[2];
  const float* b_out = (const float*)d_in[3];
  float* out = (float*)d_out;

  float* ws = (float*)d_ws;
  float* Qs = ws;                               // 4 MB fp32 [bh][n][32]
  u16* Khi  = (u16*)(ws + 1048576);             // 2 MB each
  u16* Klo  = Khi  + 1048576;
  u16* VT16 = Klo  + 1048576;
  float* AO = out;                              // in-place

  qkv_kernel<<<TOTROWS / QROWS, 384, 0, stream>>>(x, w_qkv, Qs, Khi, Klo, VT16);
  attn_kernel<<<512, 512, 0, stream>>>(Qs, Khi, Klo, VT16, AO);
  outproj_kernel<<<TOTROWS / OROWS, 128, 0, stream>>>(AO, w_out, b_out, out);
}

// Round 11
// 88.718 us; speedup vs baseline: 1.2896x; 1.2896x over previous
//
#include <hip/hip_runtime.h>
#include <math.h>

#define HEADS   4
#define DH      32
#define NB      4096      // tokens per batch (D*H*W)
#define BATCH   2
#define C_IN    128
#define QKV_COLS 384
#define TOTROWS 8192      // BATCH * NB
#define ATT_EPS 1e-12f
#define C1      14.42695040888963f   // SCALE * log2(e), prefolded into Q
#define QROWS   8         // rows per qkv block (grid 1024). R8:32 too coarse
                          // (13% occ), R10:4 too fine (w-load bound, VGPR 88,
                          // 75us). 8 = measured optimum (R9).
#define OROWS   8         // rows per outproj block (grid 1024) — same tradeoff

typedef __attribute__((ext_vector_type(16))) float f32x16;
typedef __attribute__((ext_vector_type(8)))  short short8;
typedef _Float16 f16x8 __attribute__((ext_vector_type(8)));
typedef __fp16 fp16x2 __attribute__((ext_vector_type(2)));   // cvt_pkrtz return type
typedef unsigned short u16;

__device__ __forceinline__ float tr16(float a) {        // truncate to bf16 (bits)
  return __uint_as_float(__float_as_uint(a) & 0xFFFF0000u);
}
__device__ __forceinline__ unsigned pkhi(float a, float b) {  // pack 2 bf16 (trunc)
  return (__float_as_uint(a) >> 16) | (__float_as_uint(b) & 0xFFFF0000u);
}
__device__ __forceinline__ u16 b16(float a) {
  return (u16)(__float_as_uint(a) >> 16);
}
// pack 2 f32 -> 2 f16 (RTZ), single instruction
union Uh2 { fp16x2 h; unsigned u; };
__device__ __forceinline__ unsigned pkf16(float a, float b) {
  Uh2 t; t.h = __builtin_amdgcn_cvt_pkrtz(a, b); return t.u;
}
union U8 { unsigned u[4]; short8 s8; };
__device__ __forceinline__ short8 mk8(unsigned a, unsigned b, unsigned c, unsigned d) {
  U8 t; t.u[0] = a; t.u[1] = b; t.u[2] = c; t.u[3] = d; return t.s8;
}
union U8h { unsigned u[4]; f16x8 h8; };
__device__ __forceinline__ f16x8 mk8h(unsigned a, unsigned b, unsigned c, unsigned d) {
  U8h t; t.u[0] = a; t.u[1] = b; t.u[2] = c; t.u[3] = d; return t.h8;
}
// v_permlane32_swap_b32 a,b. SAFE ONLY when a and b hold distinct values
// (else regalloc may coalesce them into one register) — see R4 post-mortem.
__device__ __forceinline__ void pl32swap(unsigned& a, unsigned& b) {
  asm("v_permlane32_swap_b32 %0, %1" : "+v"(a), "+v"(b));
}
#define GL16(gp, lp)                                                        \
  __builtin_amdgcn_global_load_lds(                                         \
      (const __attribute__((address_space(1))) void*)(gp),                  \
      (__attribute__((address_space(3))) void*)(lp), 16, 0, 0)

// ---------------------------------------------------------------------------
// QKV GEMM (x @ w_qkv) + fused L2-normalize of q,k. 8 rows/block, 1024 blocks
// (R9 config — measured good). float4 partial accumulators break the serial
// FMA dependence chain. Writes:
//   Qs  fp32 [bh][n][32], pre-scaled by C1
//   Khi/Klo u16 [bh][n][32]   (bf16 truncation hi + residual lo)
//   VT16 u16 [bh][32][n]      (fp16 RTZ, pre-transposed)
// ---------------------------------------------------------------------------
__global__ __launch_bounds__(384) void qkv_kernel(
    const float* __restrict__ x, const float* __restrict__ w,
    float* __restrict__ Qs, u16* __restrict__ Khi, u16* __restrict__ Klo,
    u16* __restrict__ VT16) {
  __shared__ float xR[QROWS][132];   // row-major tile, 528B rows (16B-aligned)
  const int tid = threadIdx.x;
  const int r0  = blockIdx.x * QROWS;

  if (tid < QROWS * 32) {
    const int r = tid >> 5, c4 = tid & 31;
    const float4 v4 = ((const float4*)(x + (size_t)(r0 + r) * C_IN))[c4];
    *(float4*)&xR[r][c4 * 4] = v4;
  }
  __syncthreads();

  float4 a4[QROWS];
#pragma unroll
  for (int r = 0; r < QROWS; ++r) a4[r] = make_float4(0.f, 0.f, 0.f, 0.f);

  for (int c4 = 0; c4 < 32; ++c4) {
    const float wv0 = w[(c4 * 4 + 0) * QKV_COLS + tid];
    const float wv1 = w[(c4 * 4 + 1) * QKV_COLS + tid];
    const float wv2 = w[(c4 * 4 + 2) * QKV_COLS + tid];
    const float wv3 = w[(c4 * 4 + 3) * QKV_COLS + tid];
#pragma unroll
    for (int r = 0; r < QROWS; ++r) {
      const float4 xv = *(const float4*)&xR[r][c4 * 4];   // broadcast read
      a4[r].x = fmaf(xv.x, wv0, a4[r].x);
      a4[r].y = fmaf(xv.y, wv1, a4[r].y);
      a4[r].z = fmaf(xv.z, wv2, a4[r].z);
      a4[r].w = fmaf(xv.w, wv3, a4[r].w);
    }
  }

  float acc[QROWS];
#pragma unroll
  for (int r = 0; r < QROWS; ++r)
    acc[r] = (a4[r].x + a4[r].y) + (a4[r].z + a4[r].w);

  const int part = tid >> 7;   // 0=q 1=k 2=v (wave-uniform)
  if (part < 2) {
#pragma unroll
    for (int r = 0; r < QROWS; ++r) {
      float s = acc[r] * acc[r];
      s += __shfl_xor(s, 1, 32);
      s += __shfl_xor(s, 2, 32);
      s += __shfl_xor(s, 4, 32);
      s += __shfl_xor(s, 8, 32);
      s += __shfl_xor(s, 16, 32);
      acc[r] *= 1.0f / fmaxf(sqrtf(s), ATT_EPS);
    }
  }

  const int h = (tid >> 5) & 3, d = tid & 31;
  const int b = r0 >> 12, n0 = r0 & (NB - 1);
  const int bh = b * HEADS + h;
  if (part == 0) {
    float* dst = Qs + ((size_t)bh * NB + n0) * DH + d;
#pragma unroll
    for (int r = 0; r < QROWS; ++r) dst[(size_t)r * DH] = acc[r] * C1;
  } else if (part == 1) {
    const size_t kb = ((size_t)bh * NB + n0) * DH + d;
#pragma unroll
    for (int r = 0; r < QROWS; ++r) {
      const float kv = acc[r];
      Khi[kb + (size_t)r * DH] = b16(kv);
      Klo[kb + (size_t)r * DH] = b16(kv - tr16(kv));
    }
  } else {
    const size_t vb = ((size_t)bh * DH + d) * NB + n0;
#pragma unroll
    for (int r = 0; r < QROWS; r += 4) {
      uint2 hv;
      hv.x = pkf16(acc[r + 0], acc[r + 1]);
      hv.y = pkf16(acc[r + 2], acc[r + 3]);
      *(uint2*)(VT16 + vb + r) = hv;
    }
  }
}

// ---------------------------------------------------------------------------
// MFMA flash attention, fixed softmax max (|q.k|<=1 after L2 norm => log2
// scores bounded by C1; 2^-C1 cancels in O/L). No max tracking, no rescale.
// grid 512 (1-D), block 512 = 8 waves = 2 q-subtiles x 4 KV-splits.
// XCD-aware decode: bh = id&7 (8 XCDs, id%8 = XCD) so each XCD's L2 caches
// exactly one bh's K/V panels (768KB << 4MB). R9 measured 26.6MB FETCH vs
// ~6MB compulsory = L2 thrash; R10 confirmed the fix (attn left top-5).
// QK^T: bf16 3-term (hi/lo); PV: fp16 single-term. (unchanged from R10)
// ---------------------------------------------------------------------------
__global__ __launch_bounds__(512, 4) void attn_kernel(
    const float* __restrict__ Qs,
    const u16* __restrict__ Khi, const u16* __restrict__ Klo,
    const u16* __restrict__ VT16, float* __restrict__ AO) {
  // [buf][split][plane: 0=Khi 1=Klo 2=V16][2048B]  = 48 KB total
  __shared__ __align__(16) char sbuf[2][4][3][2048];

  const int tid  = threadIdx.x;
  const int lane = tid & 63;
  const int w    = tid >> 6;
  const int su   = w & 3;           // KV split
  const int u    = w >> 2;          // q-subtile
  const int q    = lane & 31;
  const int hi   = lane >> 5;
  const int bh   = blockIdx.x & 7;  // XCD-pinned panel
  const int qp   = blockIdx.x >> 3; // q-pair tile 0..63

  // ---- Q fragments (hi/lo truncation split); Q pre-scaled by C1 ----
  const int nrow = qp * 64 + u * 32 + q;
  const float* qrow = Qs + ((size_t)bh * NB + nrow) * DH;
  short8 fqh[2], fql[2];
#pragma unroll
  for (int sl = 0; sl < 2; ++sl) {
    const int d0 = sl * 16 + hi * 8;
    const float4 a = *(const float4*)(qrow + d0);
    const float4 b = *(const float4*)(qrow + d0 + 4);
    fqh[sl] = mk8(pkhi(a.x, a.y), pkhi(a.z, a.w), pkhi(b.x, b.y), pkhi(b.z, b.w));
    fql[sl] = mk8(pkhi(a.x - tr16(a.x), a.y - tr16(a.y)),
                  pkhi(a.z - tr16(a.z), a.w - tr16(a.w)),
                  pkhi(b.x - tr16(b.x), b.y - tr16(b.y)),
                  pkhi(b.z - tr16(b.z), b.w - tr16(b.w)));
  }

  // ---- staging map: flat i = tid + it*512 over 12 planes x 2048B ----
  const u16* gp[3]; int gst[3], ldso[3];
#pragma unroll
  for (int it = 0; it < 3; ++it) {
    const int i    = tid + it * 512;
    const int pidx = i >> 7;            // plane 0..11 = split*3 + {Khi,Klo,V}
    const int sp   = pidx / 3;
    const int pl   = pidx - sp * 3;
    const int s    = i & 127;
    const int rtt  = s >> 2;            // row within plane (key or d)
    const int ps   = s & 3;             // physical 16B slot
    const int slot = ((ps ^ ((rtt >> 1) & 3)) << 3);   // logical, u16 units
    if (pl < 2) {   // K planes: row = key, advance 32 keys/tile
      const u16* base = pl ? Klo : Khi;
      gp[it]  = base + (size_t)bh * NB * DH + (size_t)(sp * 1024 + rtt) * DH + slot;
      gst[it] = 32 * DH;
    } else {        // V plane: row = d (NB-long), advance 32 u16/tile
      gp[it]  = VT16 + (size_t)bh * DH * NB + (size_t)rtt * NB + sp * 1024 + slot;
      gst[it] = 32;
    }
    ldso[it] = i * 16;
  }
  char* const sb = (char*)sbuf;
  auto stage = [&](int buf) {
#pragma unroll
    for (int it = 0; it < 3; ++it) {
      GL16(gp[it], sb + buf * 24576 + ldso[it]);
      gp[it] += gst[it];
    }
  };

  // read offsets (swizzled), constant per wave
  const int swq = (q >> 1) & 3;
  int koff[2];
#pragma unroll
  for (int i = 0; i < 2; ++i) koff[i] = q * 64 + (((i * 2 + hi) ^ swq) << 4);

  f32x16 oa;
#pragma unroll
  for (int r = 0; r < 16; ++r) oa[r] = 0.f;
  float lrun = 0.f;

  stage(0);
  __syncthreads();

  for (int t = 0; t < 32; ++t) {
    const int cur = t & 1;
    if (t < 31) stage(cur ^ 1);

    const char* cb  = sb + cur * 24576 + su * 6144;
    const char* ckh = cb;
    const char* ckl = cb + 2048;
    const char* cv  = cb + 4096;

    // ---- QK^T (3-term hi/lo bf16), S^T[key][q] ----
    f32x16 sa;
#pragma unroll
    for (int r = 0; r < 16; ++r) sa[r] = 0.f;
    __builtin_amdgcn_s_setprio(1);
#pragma unroll
    for (int sl = 0; sl < 2; ++sl) {
      const short8 fkh = *(const short8*)(ckh + koff[sl]);
      const short8 fkl = *(const short8*)(ckl + koff[sl]);
      sa = __builtin_amdgcn_mfma_f32_32x32x16_bf16(fkh, fqh[sl], sa, 0, 0, 0);
      sa = __builtin_amdgcn_mfma_f32_32x32x16_bf16(fkl, fqh[sl], sa, 0, 0, 0);
      sa = __builtin_amdgcn_mfma_f32_32x32x16_bf16(fkh, fql[sl], sa, 0, 0, 0);
    }
    __builtin_amdgcn_s_setprio(0);

    // ---- softmax, fixed max: raw v_exp_f32 (inputs bounded by ±2*C1) ----
    float e[16], lsum = 0.f;
#pragma unroll
    for (int r = 0; r < 16; ++r) {
      e[r] = __builtin_amdgcn_exp2f(sa[r]);
      lsum += e[r];
    }
    lrun += lsum;

    // ---- P pack (fp16 RTZ) + permlane32_swap distribution, PV 1-term ----
    __builtin_amdgcn_s_setprio(1);
#pragma unroll
    for (int m = 0; m < 2; ++m) {
      const float* eb = e + 8 * m;
      unsigned x0 = pkf16(eb[0], eb[1]), x1 = pkf16(eb[2], eb[3]);
      unsigned y0 = pkf16(eb[4], eb[5]), y1 = pkf16(eb[6], eb[7]);
      pl32swap(x0, y0);    // distinct values: safe
      pl32swap(x1, y1);
      const f16x8 fP = mk8h(x0, x1, y0, y1);
      const f16x8 fv = *(const f16x8*)(cv + koff[m]);
      oa = __builtin_amdgcn_mfma_f32_32x32x16_f16(fv, fP, oa, 0, 0, 0);
    }
    __builtin_amdgcn_s_setprio(0);
    __syncthreads();   // drains gload_lds (implicit vmcnt(0)) + LDS reads
  }

  // ---- 4-way split merge via LDS (plain sums — common fixed max) ----
  // Alias merge arrays onto the (dead) staging LDS.
  float* const mO = (float*)sbuf;             // [u][s(0..2)][q][33]
  float* const mL = mO + 2 * 3 * 32 * 33;     // [u][s][q]
  const float Lfull = lrun + __shfl_xor(lrun, 32);
  if (su != 0) {
    const int sidx = (u * 3 + (su - 1)) * 32 + q;
    if (hi == 0) mL[sidx] = Lfull;
#pragma unroll
    for (int r = 0; r < 16; ++r) {
      const int d = (r & 3) + 8 * (r >> 2) + 4 * hi;
      mO[sidx * 33 + d] = oa[r];
    }
  }
  __syncthreads();
  if (su == 0) {
    float Lt = Lfull;
#pragma unroll
    for (int s = 0; s < 3; ++s) Lt += mL[(u * 3 + s) * 32 + q];
    const float inv = 1.0f / Lt;
    const int b = bh >> 2, h = bh & 3;
    float* dst = AO + ((size_t)(b * NB + nrow)) * 128 + h * DH;
#pragma unroll
    for (int r = 0; r < 16; ++r) {
      const int d = (r & 3) + 8 * (r >> 2) + 4 * hi;
      float v = oa[r];
#pragma unroll
      for (int s = 0; s < 3; ++s) v += mO[((u * 3 + s) * 32 + q) * 33 + d];
      dst[d] = v * inv;
    }
  }
}

// ---------------------------------------------------------------------------
// out-proj GEMM: AO[8192][128] @ w_out[128][128] + b_out (in-place safe:
// block stages its 8 rows in LDS before overwriting them). 1024 blocks
// (R9 config — measured good; R10's 4-row version was w-load bound).
// ---------------------------------------------------------------------------
__global__ __launch_bounds__(128) void outproj_kernel(
    const float* __restrict__ AO, const float* __restrict__ w,
    const float* __restrict__ bias, float* __restrict__ out) {
  __shared__ float xR[OROWS][132];
  const int tid = threadIdx.x;
  const int r0  = blockIdx.x * OROWS;

  for (int i = tid; i < OROWS * 32; i += 128) {
    const int r = i >> 5, c4 = i & 31;
    const float4 v4 = ((const float4*)(AO + (size_t)(r0 + r) * 128))[c4];
    *(float4*)&xR[r][c4 * 4] = v4;
  }
  __syncthreads();

  float4 a4[OROWS];
#pragma unroll
  for (int r = 0; r < OROWS; ++r) a4[r] = make_float4(0.f, 0.f, 0.f, 0.f);

  for (int c4 = 0; c4 < 32; ++c4) {
    const float wv0 = w[(c4 * 4 + 0) * 128 + tid];
    const float wv1 = w[(c4 * 4 + 1) * 128 + tid];
    const float wv2 = w[(c4 * 4 + 2) * 128 + tid];
    const float wv3 = w[(c4 * 4 + 3) * 128 + tid];
#pragma unroll
    for (int r = 0; r < OROWS; ++r) {
      const float4 xv = *(const float4*)&xR[r][c4 * 4];   // broadcast read
      a4[r].x = fmaf(xv.x, wv0, a4[r].x);
      a4[r].y = fmaf(xv.y, wv1, a4[r].y);
      a4[r].z = fmaf(xv.z, wv2, a4[r].z);
      a4[r].w = fmaf(xv.w, wv3, a4[r].w);
    }
  }

  const float bv = bias[tid];
#pragma unroll
  for (int r = 0; r < OROWS; ++r) {
    const float acc = (a4[r].x + a4[r].y) + (a4[r].z + a4[r].w);
    out[(size_t)(r0 + r) * 128 + tid] = acc + bv;
  }
}

// ---------------------------------------------------------------------------
extern "C" void kernel_launch(void* const* d_in, const int* in_sizes, int n_in,
                              void* d_out, int out_size, void* d_ws, size_t ws_size,
                              hipStream_t stream) {
  (void)in_sizes; (void)n_in; (void)out_size; (void)ws_size;
  const float* x     = (const float*)d_in[0];
  const float* w_qkv = (const float*)d_in[1];
  const float* w_out = (const float*)d_in[2];
  const float* b_out = (const float*)d_in[3];
  float* out = (float*)d_out;

  float* ws = (float*)d_ws;
  float* Qs = ws;                               // 4 MB fp32 [bh][n][32]
  u16* Khi  = (u16*)(ws + 1048576);             // 2 MB each
  u16* Klo  = Khi  + 1048576;
  u16* VT16 = Klo  + 1048576;
  float* AO = out;                              // in-place

  qkv_kernel<<<TOTROWS / QROWS, 384, 0, stream>>>(x, w_qkv, Qs, Khi, Klo, VT16);
  attn_kernel<<<512, 512, 0, stream>>>(Qs, Khi, Klo, VT16, AO);
  outproj_kernel<<<TOTROWS / OROWS, 128, 0, stream>>>(AO, w_out, b_out, out);
}

// Round 12
// 67.831 us; speedup vs baseline: 1.6866x; 1.3079x over previous
//
#include <hip/hip_runtime.h>
#include <math.h>

#define HEADS   4
#define DH      32
#define NB      4096      // tokens per batch (D*H*W)
#define BATCH   2
#define C_IN    128
#define QKV_COLS 384
#define TOTROWS 8192      // BATCH * NB
#define ATT_EPS 1e-12f
#define C1      14.42695040888963f   // SCALE * log2(e), prefolded into Q
#define QROWS   8         // rows per qkv block (grid 1024)
#define OROWS   8         // rows per outproj block (grid 1024)

typedef __attribute__((ext_vector_type(16))) float f32x16;
typedef _Float16 f16x8 __attribute__((ext_vector_type(8)));
typedef __fp16 fp16x2 __attribute__((ext_vector_type(2)));   // cvt_pkrtz return type
typedef unsigned short u16;

// fp16 RTN conversion (default float->_Float16 rounding)
__device__ __forceinline__ u16 f16b(float a) {
  union { _Float16 h; u16 u; } t; t.h = (_Float16)a; return t.u;
}
__device__ __forceinline__ unsigned pkf16rtn(float a, float b) {
  return (unsigned)f16b(a) | ((unsigned)f16b(b) << 16);
}
// pack 2 f32 -> 2 f16 (RTZ), single instruction (P values only)
union Uh2 { fp16x2 h; unsigned u; };
__device__ __forceinline__ unsigned pkf16(float a, float b) {
  Uh2 t; t.h = __builtin_amdgcn_cvt_pkrtz(a, b); return t.u;
}
union U8h { unsigned u[4]; f16x8 h8; };
__device__ __forceinline__ f16x8 mk8h(unsigned a, unsigned b, unsigned c, unsigned d) {
  U8h t; t.u[0] = a; t.u[1] = b; t.u[2] = c; t.u[3] = d; return t.h8;
}
// v_permlane32_swap_b32 a,b. SAFE ONLY when a and b hold distinct values
// (else regalloc may coalesce them into one register) — see R4 post-mortem.
__device__ __forceinline__ void pl32swap(unsigned& a, unsigned& b) {
  asm("v_permlane32_swap_b32 %0, %1" : "+v"(a), "+v"(b));
}
#define GL16(gp, lp)                                                        \
  __builtin_amdgcn_global_load_lds(                                         \
      (const __attribute__((address_space(1))) void*)(gp),                  \
      (__attribute__((address_space(3))) void*)(lp), 16, 0, 0)

// ---------------------------------------------------------------------------
// QKV GEMM (x @ w_qkv) + fused L2-normalize of q,k. NO LDS: x-tile values are
// block-uniform -> scalar (s_load) operands; w coalesced per-lane. R11 showed
// the LDS-broadcast version was LDS-pipe-bound (256 ds_read_b128/wave ~ 30us).
// Writes:
//   Qs  fp32 [bh][n][32], pre-scaled by C1
//   K16 u16 [bh][n][32]   (fp16 RTN)
//   VT16 u16 [bh][32][n]  (fp16 RTN, pre-transposed)
// ---------------------------------------------------------------------------
__global__ __launch_bounds__(384) void qkv_kernel(
    const float* __restrict__ x, const float* __restrict__ w,
    float* __restrict__ Qs, u16* __restrict__ K16, u16* __restrict__ VT16) {
  const int tid = threadIdx.x;
  const int r0  = blockIdx.x * QROWS;

  float4 a4[QROWS];
#pragma unroll
  for (int r = 0; r < QROWS; ++r) a4[r] = make_float4(0.f, 0.f, 0.f, 0.f);

  for (int c4 = 0; c4 < 32; ++c4) {
    const float wv0 = w[(c4 * 4 + 0) * QKV_COLS + tid];
    const float wv1 = w[(c4 * 4 + 1) * QKV_COLS + tid];
    const float wv2 = w[(c4 * 4 + 2) * QKV_COLS + tid];
    const float wv3 = w[(c4 * 4 + 3) * QKV_COLS + tid];
#pragma unroll
    for (int r = 0; r < QROWS; ++r) {
      const float* xr = x + (size_t)(r0 + r) * C_IN + c4 * 4;  // uniform -> s_load
      a4[r].x = fmaf(xr[0], wv0, a4[r].x);
      a4[r].y = fmaf(xr[1], wv1, a4[r].y);
      a4[r].z = fmaf(xr[2], wv2, a4[r].z);
      a4[r].w = fmaf(xr[3], wv3, a4[r].w);
    }
  }

  float acc[QROWS];
#pragma unroll
  for (int r = 0; r < QROWS; ++r)
    acc[r] = (a4[r].x + a4[r].y) + (a4[r].z + a4[r].w);

  const int part = tid >> 7;   // 0=q 1=k 2=v (wave-uniform)
  if (part < 2) {
#pragma unroll
    for (int r = 0; r < QROWS; ++r) {
      float s = acc[r] * acc[r];
      s += __shfl_xor(s, 1, 32);
      s += __shfl_xor(s, 2, 32);
      s += __shfl_xor(s, 4, 32);
      s += __shfl_xor(s, 8, 32);
      s += __shfl_xor(s, 16, 32);
      acc[r] *= 1.0f / fmaxf(sqrtf(s), ATT_EPS);
    }
  }

  const int h = (tid >> 5) & 3, d = tid & 31;
  const int b = r0 >> 12, n0 = r0 & (NB - 1);
  const int bh = b * HEADS + h;
  if (part == 0) {
    float* dst = Qs + ((size_t)bh * NB + n0) * DH + d;
#pragma unroll
    for (int r = 0; r < QROWS; ++r) dst[(size_t)r * DH] = acc[r] * C1;
  } else if (part == 1) {
    const size_t kb = ((size_t)bh * NB + n0) * DH + d;
#pragma unroll
    for (int r = 0; r < QROWS; ++r) K16[kb + (size_t)r * DH] = f16b(acc[r]);
  } else {
    const size_t vb = ((size_t)bh * DH + d) * NB + n0;
#pragma unroll
    for (int r = 0; r < QROWS; r += 4) {
      uint2 hv;
      hv.x = pkf16rtn(acc[r + 0], acc[r + 1]);
      hv.y = pkf16rtn(acc[r + 2], acc[r + 3]);
      *(uint2*)(VT16 + vb + r) = hv;
    }
  }
}

// ---------------------------------------------------------------------------
// MFMA flash attention, fixed softmax max (|q.k|<=1 after L2 norm => log2
// scores bounded by C1; 2^-C1 cancels in O/L). No max tracking, no rescale.
// grid 512 (1-D), block 512 = 8 waves = 2 q-subtiles x 4 KV-splits.
// XCD-pinned: bh = id&7 (R11: FETCH 26.6->5.1MB).
// QK^T: fp16 single-term (R12 — was bf16 3-term; R11 showed issue-bound, so
// MFMA count 8->4/tile, staging planes 3->2); PV: fp16 single-term.
// ---------------------------------------------------------------------------
__global__ __launch_bounds__(512, 4) void attn_kernel(
    const float* __restrict__ Qs, const u16* __restrict__ K16,
    const u16* __restrict__ VT16, float* __restrict__ AO) {
  // [buf][split][plane: 0=K16 1=V16][2048B]  = 32 KB total
  __shared__ __align__(16) char sbuf[2][4][2][2048];

  const int tid  = threadIdx.x;
  const int lane = tid & 63;
  const int w    = tid >> 6;
  const int su   = w & 3;           // KV split
  const int u    = w >> 2;          // q-subtile
  const int q    = lane & 31;
  const int hi   = lane >> 5;
  const int bh   = blockIdx.x & 7;  // XCD-pinned panel
  const int qp   = blockIdx.x >> 3; // q-pair tile 0..63

  // ---- Q fragments (fp16 RTN); Q pre-scaled by C1 ----
  const int nrow = qp * 64 + u * 32 + q;
  const float* qrow = Qs + ((size_t)bh * NB + nrow) * DH;
  f16x8 fq16[2];
#pragma unroll
  for (int sl = 0; sl < 2; ++sl) {
    const int d0 = sl * 16 + hi * 8;
    const float4 a = *(const float4*)(qrow + d0);
    const float4 b = *(const float4*)(qrow + d0 + 4);
    fq16[sl] = mk8h(pkf16rtn(a.x, a.y), pkf16rtn(a.z, a.w),
                    pkf16rtn(b.x, b.y), pkf16rtn(b.z, b.w));
  }

  // ---- staging map: flat i = tid + it*512 over 8 planes x 2048B ----
  const u16* gp[2]; int gst[2], ldso[2];
#pragma unroll
  for (int it = 0; it < 2; ++it) {
    const int i    = tid + it * 512;
    const int pidx = i >> 7;            // plane 0..7 = split*2 + {K16,V16}
    const int sp   = pidx >> 1;
    const int pl   = pidx & 1;
    const int s    = i & 127;
    const int rtt  = s >> 2;            // row within plane (key or d)
    const int ps   = s & 3;             // physical 16B slot
    const int slot = ((ps ^ ((rtt >> 1) & 3)) << 3);   // logical, u16 units
    if (pl == 0) {  // K plane: row = key, advance 32 keys/tile
      gp[it]  = K16 + (size_t)bh * NB * DH + (size_t)(sp * 1024 + rtt) * DH + slot;
      gst[it] = 32 * DH;
    } else {        // V plane: row = d (NB-long), advance 32 u16/tile
      gp[it]  = VT16 + (size_t)bh * DH * NB + (size_t)rtt * NB + sp * 1024 + slot;
      gst[it] = 32;
    }
    ldso[it] = i * 16;
  }
  char* const sb = (char*)sbuf;
  auto stage = [&](int buf) {
#pragma unroll
    for (int it = 0; it < 2; ++it) {
      GL16(gp[it], sb + buf * 16384 + ldso[it]);
      gp[it] += gst[it];
    }
  };

  // read offsets (swizzled), constant per wave
  const int swq = (q >> 1) & 3;
  int koff[2];
#pragma unroll
  for (int i = 0; i < 2; ++i) koff[i] = q * 64 + (((i * 2 + hi) ^ swq) << 4);

  f32x16 oa;
#pragma unroll
  for (int r = 0; r < 16; ++r) oa[r] = 0.f;
  float lrun = 0.f;

  stage(0);
  __syncthreads();

  for (int t = 0; t < 32; ++t) {
    const int cur = t & 1;
    if (t < 31) stage(cur ^ 1);

    const char* cb = sb + cur * 16384 + su * 4096;
    const char* ck = cb;
    const char* cv = cb + 2048;

    // ---- QK^T (single-term fp16), S^T[key][q] ----
    f32x16 sa;
#pragma unroll
    for (int r = 0; r < 16; ++r) sa[r] = 0.f;
    __builtin_amdgcn_s_setprio(1);
#pragma unroll
    for (int sl = 0; sl < 2; ++sl) {
      const f16x8 fk = *(const f16x8*)(ck + koff[sl]);
      sa = __builtin_amdgcn_mfma_f32_32x32x16_f16(fk, fq16[sl], sa, 0, 0, 0);
    }
    __builtin_amdgcn_s_setprio(0);

    // ---- softmax, fixed max: raw v_exp_f32 (inputs bounded by ±~C1) ----
    float e[16], lsum = 0.f;
#pragma unroll
    for (int r = 0; r < 16; ++r) {
      e[r] = __builtin_amdgcn_exp2f(sa[r]);
      lsum += e[r];
    }
    lrun += lsum;

    // ---- P pack (fp16 RTZ) + permlane32_swap distribution, PV 1-term ----
    __builtin_amdgcn_s_setprio(1);
#pragma unroll
    for (int m = 0; m < 2; ++m) {
      const float* eb = e + 8 * m;
      unsigned x0 = pkf16(eb[0], eb[1]), x1 = pkf16(eb[2], eb[3]);
      unsigned y0 = pkf16(eb[4], eb[5]), y1 = pkf16(eb[6], eb[7]);
      pl32swap(x0, y0);    // distinct values: safe
      pl32swap(x1, y1);
      const f16x8 fP = mk8h(x0, x1, y0, y1);
      const f16x8 fv = *(const f16x8*)(cv + koff[m]);
      oa = __builtin_amdgcn_mfma_f32_32x32x16_f16(fv, fP, oa, 0, 0, 0);
    }
    __builtin_amdgcn_s_setprio(0);
    __syncthreads();   // drains gload_lds (implicit vmcnt(0)) + LDS reads
  }

  // ---- 4-way split merge via LDS (plain sums — common fixed max) ----
  // Alias merge arrays onto the (dead) staging LDS (needs ~26KB < 32KB).
  float* const mO = (float*)sbuf;             // [u][s(0..2)][q][33]
  float* const mL = mO + 2 * 3 * 32 * 33;     // [u][s][q]
  const float Lfull = lrun + __shfl_xor(lrun, 32);
  if (su != 0) {
    const int sidx = (u * 3 + (su - 1)) * 32 + q;
    if (hi == 0) mL[sidx] = Lfull;
#pragma unroll
    for (int r = 0; r < 16; ++r) {
      const int d = (r & 3) + 8 * (r >> 2) + 4 * hi;
      mO[sidx * 33 + d] = oa[r];
    }
  }
  __syncthreads();
  if (su == 0) {
    float Lt = Lfull;
#pragma unroll
    for (int s = 0; s < 3; ++s) Lt += mL[(u * 3 + s) * 32 + q];
    const float inv = 1.0f / Lt;
    const int b = bh >> 2, h = bh & 3;
    float* dst = AO + ((size_t)(b * NB + nrow)) * 128 + h * DH;
#pragma unroll
    for (int r = 0; r < 16; ++r) {
      const int d = (r & 3) + 8 * (r >> 2) + 4 * hi;
      float v = oa[r];
#pragma unroll
      for (int s = 0; s < 3; ++s) v += mO[((u * 3 + s) * 32 + q) * 33 + d];
      dst[d] = v * inv;
    }
  }
}

// ---------------------------------------------------------------------------
// out-proj GEMM: AO[8192][128] @ w_out[128][128] + b_out. NO LDS: AO rows are
// block-uniform -> scalar loads. In-place safe: all AO reads are consumed
// into acc before the barrier; stores (to the same rows) happen after it.
// ---------------------------------------------------------------------------
__global__ __launch_bounds__(128) void outproj_kernel(
    const float* __restrict__ AO, const float* __restrict__ w,
    const float* __restrict__ bias, float* __restrict__ out) {
  const int tid = threadIdx.x;
  const int r0  = blockIdx.x * OROWS;

  float4 a4[OROWS];
#pragma unroll
  for (int r = 0; r < OROWS; ++r) a4[r] = make_float4(0.f, 0.f, 0.f, 0.f);

  for (int c4 = 0; c4 < 32; ++c4) {
    const float wv0 = w[(c4 * 4 + 0) * 128 + tid];
    const float wv1 = w[(c4 * 4 + 1) * 128 + tid];
    const float wv2 = w[(c4 * 4 + 2) * 128 + tid];
    const float wv3 = w[(c4 * 4 + 3) * 128 + tid];
#pragma unroll
    for (int r = 0; r < OROWS; ++r) {
      const float* xr = AO + (size_t)(r0 + r) * 128 + c4 * 4;  // uniform -> s_load
      a4[r].x = fmaf(xr[0], wv0, a4[r].x);
      a4[r].y = fmaf(xr[1], wv1, a4[r].y);
      a4[r].z = fmaf(xr[2], wv2, a4[r].z);
      a4[r].w = fmaf(xr[3], wv3, a4[r].w);
    }
  }

  __syncthreads();   // all AO reads of this block's rows complete before stores

  const float bv = bias[tid];
#pragma unroll
  for (int r = 0; r < OROWS; ++r) {
    const float acc = (a4[r].x + a4[r].y) + (a4[r].z + a4[r].w);
    out[(size_t)(r0 + r) * 128 + tid] = acc + bv;
  }
}

// ---------------------------------------------------------------------------
extern "C" void kernel_launch(void* const* d_in, const int* in_sizes, int n_in,
                              void* d_out, int out_size, void* d_ws, size_t ws_size,
                              hipStream_t stream) {
  (void)in_sizes; (void)n_in; (void)out_size; (void)ws_size;
  const float* x     = (const float*)d_in[0];
  const float* w_qkv = (const float*)d_in[1];
  const float* w_out = (const float*)d_in[2];
  const float* b_out = (const float*)d_in[3];
  float* out = (float*)d_out;

  float* ws = (float*)d_ws;
  float* Qs = ws;                               // 4 MB fp32 [bh][n][32]
  u16* K16  = (u16*)(ws + 1048576);             // 2 MB
  u16* VT16 = K16 + 1048576;                    // 2 MB
  float* AO = out;                              // in-place

  qkv_kernel<<<TOTROWS / QROWS, 384, 0, stream>>>(x, w_qkv, Qs, K16, VT16);
  attn_kernel<<<512, 512, 0, stream>>>(Qs, K16, VT16, AO);
  outproj_kernel<<<TOTROWS / OROWS, 128, 0, stream>>>(AO, w_out, b_out, out);
}

// Round 13
// 66.740 us; speedup vs baseline: 1.7142x; 1.0163x over previous
//
#include <hip/hip_runtime.h>
#include <math.h>

#define HEADS   4
#define DH      32
#define NB      4096      // tokens per batch (D*H*W)
#define BATCH   2
#define C_IN    128
#define QKV_COLS 384
#define TOTROWS 8192      // BATCH * NB
#define ATT_EPS 1e-12f
#define C1      14.42695040888963f   // SCALE * log2(e), prefolded into Q
#define QROWS   8         // rows per qkv block (grid 1024)
#define OROWS   8         // rows per outproj block (grid 1024)

typedef __attribute__((ext_vector_type(16))) float f32x16;
typedef _Float16 f16x8 __attribute__((ext_vector_type(8)));
typedef __fp16 fp16x2 __attribute__((ext_vector_type(2)));   // cvt_pkrtz return type
typedef unsigned short u16;

// fp16 RTN conversion (default float->_Float16 rounding)
__device__ __forceinline__ u16 f16b(float a) {
  union { _Float16 h; u16 u; } t; t.h = (_Float16)a; return t.u;
}
__device__ __forceinline__ unsigned pkf16rtn(float a, float b) {
  return (unsigned)f16b(a) | ((unsigned)f16b(b) << 16);
}
// pack 2 f32 -> 2 f16 (RTZ), single instruction (P values only)
union Uh2 { fp16x2 h; unsigned u; };
__device__ __forceinline__ unsigned pkf16(float a, float b) {
  Uh2 t; t.h = __builtin_amdgcn_cvt_pkrtz(a, b); return t.u;
}
union U8h { unsigned u[4]; f16x8 h8; };
__device__ __forceinline__ f16x8 mk8h(unsigned a, unsigned b, unsigned c, unsigned d) {
  U8h t; t.u[0] = a; t.u[1] = b; t.u[2] = c; t.u[3] = d; return t.h8;
}
// v_permlane32_swap_b32 a,b. SAFE ONLY when a and b hold distinct values
// (else regalloc may coalesce them into one register) — see R4 post-mortem.
__device__ __forceinline__ void pl32swap(unsigned& a, unsigned& b) {
  asm("v_permlane32_swap_b32 %0, %1" : "+v"(a), "+v"(b));
}
#define GL16(gp, lp)                                                        \
  __builtin_amdgcn_global_load_lds(                                         \
      (const __attribute__((address_space(1))) void*)(gp),                  \
      (__attribute__((address_space(3))) void*)(lp), 16, 0, 0)

// ---------------------------------------------------------------------------
// QKV GEMM (x @ w_qkv) + fused L2-normalize of q,k. NO LDS (R12: scalar x
// loads; LDS-broadcast version was LDS-pipe-bound). Unchanged from R12.
// ---------------------------------------------------------------------------
__global__ __launch_bounds__(384) void qkv_kernel(
    const float* __restrict__ x, const float* __restrict__ w,
    float* __restrict__ Qs, u16* __restrict__ K16, u16* __restrict__ VT16) {
  const int tid = threadIdx.x;
  const int r0  = blockIdx.x * QROWS;

  float4 a4[QROWS];
#pragma unroll
  for (int r = 0; r < QROWS; ++r) a4[r] = make_float4(0.f, 0.f, 0.f, 0.f);

  for (int c4 = 0; c4 < 32; ++c4) {
    const float wv0 = w[(c4 * 4 + 0) * QKV_COLS + tid];
    const float wv1 = w[(c4 * 4 + 1) * QKV_COLS + tid];
    const float wv2 = w[(c4 * 4 + 2) * QKV_COLS + tid];
    const float wv3 = w[(c4 * 4 + 3) * QKV_COLS + tid];
#pragma unroll
    for (int r = 0; r < QROWS; ++r) {
      const float* xr = x + (size_t)(r0 + r) * C_IN + c4 * 4;  // uniform -> s_load
      a4[r].x = fmaf(xr[0], wv0, a4[r].x);
      a4[r].y = fmaf(xr[1], wv1, a4[r].y);
      a4[r].z = fmaf(xr[2], wv2, a4[r].z);
      a4[r].w = fmaf(xr[3], wv3, a4[r].w);
    }
  }

  float acc[QROWS];
#pragma unroll
  for (int r = 0; r < QROWS; ++r)
    acc[r] = (a4[r].x + a4[r].y) + (a4[r].z + a4[r].w);

  const int part = tid >> 7;   // 0=q 1=k 2=v (wave-uniform)
  if (part < 2) {
#pragma unroll
    for (int r = 0; r < QROWS; ++r) {
      float s = acc[r] * acc[r];
      s += __shfl_xor(s, 1, 32);
      s += __shfl_xor(s, 2, 32);
      s += __shfl_xor(s, 4, 32);
      s += __shfl_xor(s, 8, 32);
      s += __shfl_xor(s, 16, 32);
      acc[r] *= 1.0f / fmaxf(sqrtf(s), ATT_EPS);
    }
  }

  const int h = (tid >> 5) & 3, d = tid & 31;
  const int b = r0 >> 12, n0 = r0 & (NB - 1);
  const int bh = b * HEADS + h;
  if (part == 0) {
    float* dst = Qs + ((size_t)bh * NB + n0) * DH + d;
#pragma unroll
    for (int r = 0; r < QROWS; ++r) dst[(size_t)r * DH] = acc[r] * C1;
  } else if (part == 1) {
    const size_t kb = ((size_t)bh * NB + n0) * DH + d;
#pragma unroll
    for (int r = 0; r < QROWS; ++r) K16[kb + (size_t)r * DH] = f16b(acc[r]);
  } else {
    const size_t vb = ((size_t)bh * DH + d) * NB + n0;
#pragma unroll
    for (int r = 0; r < QROWS; r += 4) {
      uint2 hv;
      hv.x = pkf16rtn(acc[r + 0], acc[r + 1]);
      hv.y = pkf16rtn(acc[r + 2], acc[r + 3]);
      *(uint2*)(VT16 + vb + r) = hv;
    }
  }
}

// ---------------------------------------------------------------------------
// MFMA flash attention, fixed softmax max (|q.k|<=1 after L2 norm => log2
// scores bounded by C1; 2^-C1 cancels in O/L). No max tracking, no rescale.
// grid 512 (1-D), block 512 = 8 waves = 2 q-subtiles x 4 KV-splits.
// XCD-pinned: bh = id&7 (R11: FETCH 26.6->5.1MB).
// R13: 64-key iterations (2 sub-tiles/pass) -> barriers 32->16, double
// prefetch window; zero-const MFMA C operand removes per-tile sa zeroing.
// QK^T and PV: fp16 single-term (R12).
// ---------------------------------------------------------------------------
__global__ __launch_bounds__(512, 4) void attn_kernel(
    const float* __restrict__ Qs, const u16* __restrict__ K16,
    const u16* __restrict__ VT16, float* __restrict__ AO) {
  // [buf][split][code: 0=K sub0, 1=K sub1, 2=V sub0, 3=V sub1][2048B] = 64 KB
  __shared__ __align__(16) char sbuf[2][4][4][2048];

  const int tid  = threadIdx.x;
  const int lane = tid & 63;
  const int w    = tid >> 6;
  const int su   = w & 3;           // KV split
  const int u    = w >> 2;          // q-subtile
  const int q    = lane & 31;
  const int hi   = lane >> 5;
  const int bh   = blockIdx.x & 7;  // XCD-pinned panel
  const int qp   = blockIdx.x >> 3; // q-pair tile 0..63

  // ---- Q fragments (fp16 RTN); Q pre-scaled by C1 ----
  const int nrow = qp * 64 + u * 32 + q;
  const float* qrow = Qs + ((size_t)bh * NB + nrow) * DH;
  f16x8 fq16[2];
#pragma unroll
  for (int sl = 0; sl < 2; ++sl) {
    const int d0 = sl * 16 + hi * 8;
    const float4 a = *(const float4*)(qrow + d0);
    const float4 b = *(const float4*)(qrow + d0 + 4);
    fq16[sl] = mk8h(pkf16rtn(a.x, a.y), pkf16rtn(a.z, a.w),
                    pkf16rtn(b.x, b.y), pkf16rtn(b.z, b.w));
  }

  // ---- staging map: flat i = tid + it*512 over 16 subplanes x 2048B ----
  const u16* gp[4]; int gst[4], ldso[4];
#pragma unroll
  for (int it = 0; it < 4; ++it) {
    const int i    = tid + it * 512;    // 0..2047
    const int pidx = i >> 7;            // subplane 0..15
    const int sp   = pidx >> 2;         // split
    const int code = pidx & 3;          // 0=K0 1=K1 2=V0 3=V1
    const int pl   = code >> 1;
    const int sub  = code & 1;
    const int s    = i & 127;
    const int rtt  = s >> 2;            // row within subplane (key or d)
    const int ps   = s & 3;             // physical 16B slot
    const int slot = ((ps ^ ((rtt >> 1) & 3)) << 3);   // u16 units
    if (pl == 0) {  // K subplane: row = key, iteration advances 64 keys
      gp[it]  = K16 + (size_t)bh * NB * DH
                    + (size_t)(sp * 1024 + sub * 32 + rtt) * DH + slot;
      gst[it] = 64 * DH;
    } else {        // V subplane: row = d (NB-long), advances 64 u16
      gp[it]  = VT16 + (size_t)bh * DH * NB + (size_t)rtt * NB
                     + sp * 1024 + sub * 32 + slot;
      gst[it] = 64;
    }
    ldso[it] = i * 16;
  }
  char* const sb = (char*)sbuf;
  auto stage = [&](int buf) {
#pragma unroll
    for (int it = 0; it < 4; ++it) {
      GL16(gp[it], sb + buf * 32768 + ldso[it]);
      gp[it] += gst[it];
    }
  };

  // read offsets (swizzled), constant per wave
  const int swq = (q >> 1) & 3;
  int koff[2];
#pragma unroll
  for (int i = 0; i < 2; ++i) koff[i] = q * 64 + (((i * 2 + hi) ^ swq) << 4);

  f32x16 oa, zz;
#pragma unroll
  for (int r = 0; r < 16; ++r) { oa[r] = 0.f; zz[r] = 0.f; }
  float lrun = 0.f;

  stage(0);
  __syncthreads();

  for (int t = 0; t < 16; ++t) {
    const int cur = t & 1;
    if (t < 15) stage(cur ^ 1);

    const char* cb = sb + cur * 32768 + su * 8192;

#pragma unroll
    for (int sub = 0; sub < 2; ++sub) {
      const char* ck = cb + sub * 2048;
      const char* cv = cb + 4096 + sub * 2048;

      // ---- QK^T (single-term fp16), S^T[key][q]; C-in = const zero ----
      f32x16 sa;
      __builtin_amdgcn_s_setprio(1);
      {
        const f16x8 fk0 = *(const f16x8*)(ck + koff[0]);
        const f16x8 fk1 = *(const f16x8*)(ck + koff[1]);
        sa = __builtin_amdgcn_mfma_f32_32x32x16_f16(fk0, fq16[0], zz, 0, 0, 0);
        sa = __builtin_amdgcn_mfma_f32_32x32x16_f16(fk1, fq16[1], sa, 0, 0, 0);
      }
      __builtin_amdgcn_s_setprio(0);

      // ---- softmax, fixed max: raw v_exp_f32 (inputs bounded by ±~C1) ----
      float e[16], lsum = 0.f;
#pragma unroll
      for (int r = 0; r < 16; ++r) {
        e[r] = __builtin_amdgcn_exp2f(sa[r]);
        lsum += e[r];
      }
      lrun += lsum;

      // ---- P pack (fp16 RTZ) + permlane32_swap distribution, PV 1-term ----
      __builtin_amdgcn_s_setprio(1);
#pragma unroll
      for (int m = 0; m < 2; ++m) {
        const float* eb = e + 8 * m;
        unsigned x0 = pkf16(eb[0], eb[1]), x1 = pkf16(eb[2], eb[3]);
        unsigned y0 = pkf16(eb[4], eb[5]), y1 = pkf16(eb[6], eb[7]);
        pl32swap(x0, y0);    // distinct values: safe
        pl32swap(x1, y1);
        const f16x8 fP = mk8h(x0, x1, y0, y1);
        const f16x8 fv = *(const f16x8*)(cv + koff[m]);
        oa = __builtin_amdgcn_mfma_f32_32x32x16_f16(fv, fP, oa, 0, 0, 0);
      }
      __builtin_amdgcn_s_setprio(0);
    }
    __syncthreads();   // drains gload_lds (implicit vmcnt(0)) + LDS reads
  }

  // ---- 4-way split merge via LDS (plain sums — common fixed max) ----
  // Alias merge arrays onto the (dead) staging LDS (needs ~26KB < 64KB).
  float* const mO = (float*)sbuf;             // [u][s(0..2)][q][33]
  float* const mL = mO + 2 * 3 * 32 * 33;     // [u][s][q]
  const float Lfull = lrun + __shfl_xor(lrun, 32);
  if (su != 0) {
    const int sidx = (u * 3 + (su - 1)) * 32 + q;
    if (hi == 0) mL[sidx] = Lfull;
#pragma unroll
    for (int r = 0; r < 16; ++r) {
      const int d = (r & 3) + 8 * (r >> 2) + 4 * hi;
      mO[sidx * 33 + d] = oa[r];
    }
  }
  __syncthreads();
  if (su == 0) {
    float Lt = Lfull;
#pragma unroll
    for (int s = 0; s < 3; ++s) Lt += mL[(u * 3 + s) * 32 + q];
    const float inv = 1.0f / Lt;
    const int b = bh >> 2, h = bh & 3;
    float* dst = AO + ((size_t)(b * NB + nrow)) * 128 + h * DH;
#pragma unroll
    for (int r = 0; r < 16; ++r) {
      const int d = (r & 3) + 8 * (r >> 2) + 4 * hi;
      float v = oa[r];
#pragma unroll
      for (int s = 0; s < 3; ++s) v += mO[((u * 3 + s) * 32 + q) * 33 + d];
      dst[d] = v * inv;
    }
  }
}

// ---------------------------------------------------------------------------
// out-proj GEMM: AO[8192][128] @ w_out[128][128] + b_out. NO LDS (R12).
// In-place safe: all AO reads complete before the barrier; stores after.
// ---------------------------------------------------------------------------
__global__ __launch_bounds__(128) void outproj_kernel(
    const float* __restrict__ AO, const float* __restrict__ w,
    const float* __restrict__ bias, float* __restrict__ out) {
  const int tid = threadIdx.x;
  const int r0  = blockIdx.x * OROWS;

  float4 a4[OROWS];
#pragma unroll
  for (int r = 0; r < OROWS; ++r) a4[r] = make_float4(0.f, 0.f, 0.f, 0.f);

  for (int c4 = 0; c4 < 32; ++c4) {
    const float wv0 = w[(c4 * 4 + 0) * 128 + tid];
    const float wv1 = w[(c4 * 4 + 1) * 128 + tid];
    const float wv2 = w[(c4 * 4 + 2) * 128 + tid];
    const float wv3 = w[(c4 * 4 + 3) * 128 + tid];
#pragma unroll
    for (int r = 0; r < OROWS; ++r) {
      const float* xr = AO + (size_t)(r0 + r) * 128 + c4 * 4;  // uniform -> s_load
      a4[r].x = fmaf(xr[0], wv0, a4[r].x);
      a4[r].y = fmaf(xr[1], wv1, a4[r].y);
      a4[r].z = fmaf(xr[2], wv2, a4[r].z);
      a4[r].w = fmaf(xr[3], wv3, a4[r].w);
    }
  }

  __syncthreads();   // all AO reads of this block's rows complete before stores

  const float bv = bias[tid];
#pragma unroll
  for (int r = 0; r < OROWS; ++r) {
    const float acc = (a4[r].x + a4[r].y) + (a4[r].z + a4[r].w);
    out[(size_t)(r0 + r) * 128 + tid] = acc + bv;
  }
}

// ---------------------------------------------------------------------------
extern "C" void kernel_launch(void* const* d_in, const int* in_sizes, int n_in,
                              void* d_out, int out_size, void* d_ws, size_t ws_size,
                              hipStream_t stream) {
  (void)in_sizes; (void)n_in; (void)out_size; (void)ws_size;
  const float* x     = (const float*)d_in[0];
  const float* w_qkv = (const float*)d_in[1];
  const float* w_out = (const float*)d_in[2];
  const float* b_out = (const float*)d_in[3];
  float* out = (float*)d_out;

  float* ws = (float*)d_ws;
  float* Qs = ws;                               // 4 MB fp32 [bh][n][32]
  u16* K16  = (u16*)(ws + 1048576);             // 2 MB
  u16* VT16 = K16 + 1048576;                    // 2 MB
  float* AO = out;                              // in-place

  qkv_kernel<<<TOTROWS / QROWS, 384, 0, stream>>>(x, w_qkv, Qs, K16, VT16);
  attn_kernel<<<512, 512, 0, stream>>>(Qs, K16, VT16, AO);
  outproj_kernel<<<TOTROWS / OROWS, 128, 0, stream>>>(AO, w_out, b_out, out);
}